// Round 1
// baseline (1212.983 us; speedup 1.0000x reference)
//
#include <hip/hip_runtime.h>

#define NN 50000
#define EE 1600000
#define BBATCH 256
#define DD 64

typedef _Float16 f16;
typedef _Float16 f16x8 __attribute__((ext_vector_type(8)));
typedef float f32x4 __attribute__((ext_vector_type(4)));

#define MFMA16(a,b,c) __builtin_amdgcn_mfma_f32_16x16x32_f16((a),(b),(c),0,0,0)

// ---------------- LDS layouts (in halves) ----------------
// Edge kernel: W1 [128][256->264], W2 [128][128->136], W3 [64][128->136], h 4x[32][136]
constexpr int EW1_RL  = 264;
constexpr int EW1_OFF = 0;
constexpr int EW2_OFF = EW1_OFF + 128 * EW1_RL;   // 33792
constexpr int EW3_OFF = EW2_OFF + 128 * 136;      // 51200
constexpr int EH_OFF  = EW3_OFF + 64 * 136;       // 59904
constexpr int ELDS    = EH_OFF + 4 * 32 * 136;    // 77312 halves = 154624 B

// Node/global kernel: W1 [128][192->200], W2 [128][136], W3 [64][136], h 4x[32][136]
constexpr int NW1_RL  = 200;
constexpr int NW1_OFF = 0;
constexpr int NW2_OFF = NW1_OFF + 128 * NW1_RL;   // 25600
constexpr int NW3_OFF = NW2_OFF + 128 * 136;      // 43008
constexpr int NH_OFF  = NW3_OFF + 64 * 136;       // 51712
constexpr int NLDS    = NH_OFF + 4 * 32 * 136;    // 69120 halves = 138240 B

// ---------------- helpers ----------------
__device__ __forceinline__ f16x8 pack8(const float* __restrict__ p) {
  f32x4 a = *(const f32x4*)p;
  f32x4 b = *(const f32x4*)(p + 4);
  f16x8 r;
  r[0]=(f16)a[0]; r[1]=(f16)a[1]; r[2]=(f16)a[2]; r[3]=(f16)a[3];
  r[4]=(f16)b[0]; r[5]=(f16)b[1]; r[6]=(f16)b[2]; r[7]=(f16)b[3];
  return r;
}
__device__ __forceinline__ f16x8 pack8s(const float* __restrict__ p, float sc) {
  f32x4 a = *(const f32x4*)p;
  f32x4 b = *(const f32x4*)(p + 4);
  a = a * sc; b = b * sc;
  f16x8 r;
  r[0]=(f16)a[0]; r[1]=(f16)a[1]; r[2]=(f16)a[2]; r[3]=(f16)a[3];
  r[4]=(f16)b[0]; r[5]=(f16)b[1]; r[6]=(f16)b[2]; r[7]=(f16)b[3];
  return r;
}

// 3-layer MLP core. A layout: m=lane&15, k=(lane>>4)*8+j (verified learn_hip m89).
// Weights stored transposed [out][in] in LDS (B^T), so B-frag = contiguous 8 halves.
// D layout: n=lane&15, m=(lane>>4)*4+reg. h tile is wave-private -> no barriers.
template<int KSL, int W1RL, int W1O, int W2O, int W3O>
__device__ __forceinline__ void mlp3_core(f16* __restrict__ sm,
    const f16x8 (&A1)[2][8], const float (&b1v)[8], const float (&b2v)[8],
    const int hb, const int r15, const int g, f32x4 (&acc3)[2][4])
{
  f32x4 acc1[2][8];
  #pragma unroll
  for (int mt = 0; mt < 2; ++mt)
    #pragma unroll
    for (int nt = 0; nt < 8; ++nt)
      acc1[mt][nt] = (f32x4){0.f, 0.f, 0.f, 0.f};

  #pragma unroll
  for (int s = 0; s < KSL; ++s) {
    #pragma unroll
    for (int nt = 0; nt < 8; ++nt) {
      const f16x8 bf = *(const f16x8*)&sm[W1O + (nt*16 + r15) * W1RL + s*32 + g*8];
      acc1[0][nt] = MFMA16(A1[0][s], bf, acc1[0][nt]);
      acc1[1][nt] = MFMA16(A1[1][s], bf, acc1[1][nt]);
    }
  }
  // bias + relu -> h (f16)
  #pragma unroll
  for (int mt = 0; mt < 2; ++mt)
    #pragma unroll
    for (int nt = 0; nt < 8; ++nt)
      #pragma unroll
      for (int i = 0; i < 4; ++i)
        sm[hb + (mt*16 + g*4 + i)*136 + nt*16 + r15] =
            (f16)fmaxf(acc1[mt][nt][i] + b1v[nt], 0.f);

  // layer 2 (K=128)
  f16x8 A2[2][4];
  #pragma unroll
  for (int mt = 0; mt < 2; ++mt)
    #pragma unroll
    for (int s = 0; s < 4; ++s)
      A2[mt][s] = *(const f16x8*)&sm[hb + (mt*16 + r15)*136 + s*32 + g*8];

  f32x4 acc2[2][8];
  #pragma unroll
  for (int mt = 0; mt < 2; ++mt)
    #pragma unroll
    for (int nt = 0; nt < 8; ++nt)
      acc2[mt][nt] = (f32x4){0.f, 0.f, 0.f, 0.f};

  #pragma unroll
  for (int s = 0; s < 4; ++s) {
    #pragma unroll
    for (int nt = 0; nt < 8; ++nt) {
      const f16x8 bf = *(const f16x8*)&sm[W2O + (nt*16 + r15)*136 + s*32 + g*8];
      acc2[0][nt] = MFMA16(A2[0][s], bf, acc2[0][nt]);
      acc2[1][nt] = MFMA16(A2[1][s], bf, acc2[1][nt]);
    }
  }
  #pragma unroll
  for (int mt = 0; mt < 2; ++mt)
    #pragma unroll
    for (int nt = 0; nt < 8; ++nt)
      #pragma unroll
      for (int i = 0; i < 4; ++i)
        sm[hb + (mt*16 + g*4 + i)*136 + nt*16 + r15] =
            (f16)fmaxf(acc2[mt][nt][i] + b2v[nt], 0.f);

  // layer 3 (K=128, N=64)
  f16x8 A3[2][4];
  #pragma unroll
  for (int mt = 0; mt < 2; ++mt)
    #pragma unroll
    for (int s = 0; s < 4; ++s)
      A3[mt][s] = *(const f16x8*)&sm[hb + (mt*16 + r15)*136 + s*32 + g*8];

  #pragma unroll
  for (int mt = 0; mt < 2; ++mt)
    #pragma unroll
    for (int nt = 0; nt < 4; ++nt)
      acc3[mt][nt] = (f32x4){0.f, 0.f, 0.f, 0.f};

  #pragma unroll
  for (int s = 0; s < 4; ++s) {
    #pragma unroll
    for (int nt = 0; nt < 4; ++nt) {
      const f16x8 bf = *(const f16x8*)&sm[W3O + (nt*16 + r15)*136 + s*32 + g*8];
      acc3[0][nt] = MFMA16(A3[0][s], bf, acc3[0][nt]);
      acc3[1][nt] = MFMA16(A3[1][s], bf, acc3[1][nt]);
    }
  }
}

// ---------------- weight prep: transpose f32 [in][out] -> f16 [out][in] ----------------
__global__ void transpose_cvt(const float* __restrict__ w, f16* __restrict__ wt,
                              int in_dim, int out_dim) {
  int tid = blockIdx.x * 256 + threadIdx.x;
  int total = in_dim * out_dim;
  if (tid < total) {
    int o = tid / in_dim, i = tid - o * in_dim;
    wt[tid] = (f16)w[(size_t)i * out_dim + o];
  }
}

// ---------------- CSR build ----------------
__global__ void count_kernel(const int* __restrict__ ei, int* __restrict__ deg) {
  int tid = blockIdx.x * 256 + threadIdx.x;
  if (tid < EE) atomicAdd(&deg[ei[tid]], 1);
}

__global__ __launch_bounds__(1024) void scan_kernel(const int* __restrict__ deg,
                                                    int* __restrict__ offs,
                                                    int* __restrict__ cursor) {
  const int t = threadIdx.x;
  const int per = (NN + 1023) / 1024;
  const int s0 = t * per;
  int s1 = s0 + per; if (s1 > NN) s1 = NN;
  int sum = 0;
  for (int i = s0; i < s1; ++i) sum += deg[i];
  const int lane = t & 63, wid = t >> 6;
  int v = sum;
  #pragma unroll
  for (int off = 1; off < 64; off <<= 1) {
    int o = __shfl_up(v, off);
    if (lane >= off) v += o;
  }
  __shared__ int wsums[16];
  __shared__ int wexcl[16];
  if (lane == 63) wsums[wid] = v;
  __syncthreads();
  if (t == 0) { int run = 0; for (int k = 0; k < 16; ++k) { wexcl[k] = run; run += wsums[k]; } }
  __syncthreads();
  int run = wexcl[wid] + v - sum;
  for (int i = s0; i < s1; ++i) { int d = deg[i]; offs[i] = run; cursor[i] = run; run += d; }
  if (t == 1023) offs[NN] = run;
}

__global__ void fill_kernel(const int* __restrict__ ei, int* __restrict__ cursor,
                            int* __restrict__ elist) {
  int tid = blockIdx.x * 256 + threadIdx.x;
  if (tid < EE) {
    int r = ei[tid];
    int pos = atomicAdd(&cursor[r], 1);
    elist[pos] = tid;
  }
}

// ---------------- edge MLP (the big one) ----------------
__global__ __launch_bounds__(256, 1) void edge_mlp_kernel(
    const float* __restrict__ x, const float* __restrict__ ea,
    const float* __restrict__ u, const int* __restrict__ ei,
    const int* __restrict__ batch,
    const f16* __restrict__ w1t, const f16* __restrict__ w2t, const f16* __restrict__ w3t,
    const float* __restrict__ b1, const float* __restrict__ b2, const float* __restrict__ b3,
    float* __restrict__ e_out)
{
  __shared__ __align__(16) f16 sm[ELDS];
  const int t = threadIdx.x;
  // stage f16 weights into padded LDS (once per persistent block)
  for (int c = t; c < 4096; c += 256) { int r = c >> 5, kc = c & 31;
    *(uint4*)&sm[EW1_OFF + r*EW1_RL + kc*8] = *(const uint4*)&w1t[r*256 + kc*8]; }
  for (int c = t; c < 2048; c += 256) { int r = c >> 4, kc = c & 15;
    *(uint4*)&sm[EW2_OFF + r*136 + kc*8] = *(const uint4*)&w2t[r*128 + kc*8]; }
  for (int c = t; c < 1024; c += 256) { int r = c >> 4, kc = c & 15;
    *(uint4*)&sm[EW3_OFF + r*136 + kc*8] = *(const uint4*)&w3t[r*128 + kc*8]; }
  __syncthreads();

  const int l = t & 63, w = t >> 6;
  const int r15 = l & 15, g = l >> 4;
  float b1v[8], b2v[8], b3v[4];
  #pragma unroll
  for (int nt = 0; nt < 8; ++nt) { b1v[nt] = b1[nt*16 + r15]; b2v[nt] = b2[nt*16 + r15]; }
  #pragma unroll
  for (int nt = 0; nt < 4; ++nt) b3v[nt] = b3[nt*16 + r15];
  const int hb = EH_OFF + w * (32 * 136);

  for (int tile = blockIdx.x; tile < EE / 128; tile += gridDim.x) {
    const int base = tile * 128 + w * 32;
    f16x8 A1[2][8];
    #pragma unroll
    for (int mt = 0; mt < 2; ++mt) {
      const int eid = base + mt * 16 + r15;
      const int row = ei[eid], cold = ei[EE + eid];
      const int bb = batch[row];
      const float* s0p = x + (size_t)row * 64;
      const float* s1p = x + (size_t)cold * 64;
      const float* s2p = ea + (size_t)eid * 64;
      const float* s3p = u + (size_t)bb * 64;
      #pragma unroll
      for (int s = 0; s < 8; ++s) {
        const float* p = (s < 2 ? s0p : s < 4 ? s1p : s < 6 ? s2p : s3p) + (s & 1) * 32 + g * 8;
        A1[mt][s] = pack8(p);
      }
    }
    f32x4 acc3[2][4];
    mlp3_core<8, EW1_RL, EW1_OFF, EW2_OFF, EW3_OFF>(sm, A1, b1v, b2v, hb, r15, g, acc3);
    #pragma unroll
    for (int mt = 0; mt < 2; ++mt)
      #pragma unroll
      for (int nt = 0; nt < 4; ++nt)
        #pragma unroll
        for (int i = 0; i < 4; ++i) {
          const int m = base + mt * 16 + g * 4 + i;
          e_out[(size_t)m * 64 + nt * 16 + r15] = acc3[mt][nt][i] + b3v[nt];
        }
  }
}

// ---------------- n_agg sums via CSR gather ----------------
__global__ void nsum_kernel(const float* __restrict__ e_src, const int* __restrict__ offs,
                            const int* __restrict__ elist, float* __restrict__ n_sum) {
  const int l = threadIdx.x & 63;
  const int wid = (blockIdx.x * blockDim.x + threadIdx.x) >> 6;
  const int nw = (gridDim.x * blockDim.x) >> 6;
  for (int node = wid; node < NN; node += nw) {
    const int s = offs[node], e = offs[node + 1];
    float acc = 0.f;
    for (int j = s; j < e; ++j) {
      const int eid = elist[j];
      acc += e_src[(size_t)eid * 64 + l];
    }
    n_sum[(size_t)node * 64 + l] = acc;
  }
}

// ---------------- node MLP ----------------
__global__ __launch_bounds__(256, 1) void node_mlp_kernel(
    const float* __restrict__ x, const float* __restrict__ u,
    const int* __restrict__ batch, const float* __restrict__ n_sum,
    const int* __restrict__ deg,
    const f16* __restrict__ w1t, const f16* __restrict__ w2t, const f16* __restrict__ w3t,
    const float* __restrict__ b1, const float* __restrict__ b2, const float* __restrict__ b3,
    float* __restrict__ xn_out)
{
  __shared__ __align__(16) f16 sm[NLDS];
  const int t = threadIdx.x;
  for (int c = t; c < 3072; c += 256) { int r = c / 24, kc = c - r * 24;
    *(uint4*)&sm[NW1_OFF + r*NW1_RL + kc*8] = *(const uint4*)&w1t[r*192 + kc*8]; }
  for (int c = t; c < 2048; c += 256) { int r = c >> 4, kc = c & 15;
    *(uint4*)&sm[NW2_OFF + r*136 + kc*8] = *(const uint4*)&w2t[r*128 + kc*8]; }
  for (int c = t; c < 1024; c += 256) { int r = c >> 4, kc = c & 15;
    *(uint4*)&sm[NW3_OFF + r*136 + kc*8] = *(const uint4*)&w3t[r*128 + kc*8]; }
  __syncthreads();

  const int l = t & 63, w = t >> 6;
  const int r15 = l & 15, g = l >> 4;
  float b1v[8], b2v[8], b3v[4];
  #pragma unroll
  for (int nt = 0; nt < 8; ++nt) { b1v[nt] = b1[nt*16 + r15]; b2v[nt] = b2[nt*16 + r15]; }
  #pragma unroll
  for (int nt = 0; nt < 4; ++nt) b3v[nt] = b3[nt*16 + r15];
  const int hb = NH_OFF + w * (32 * 136);
  const int base = blockIdx.x * 128 + w * 32;

  f16x8 A1[2][8];
  #pragma unroll
  for (int mt = 0; mt < 2; ++mt) {
    int raw = base + mt * 16 + r15;
    int node = raw < NN ? raw : NN - 1;
    float inv = 1.0f / fmaxf((float)deg[node], 1.0f);
    const float* sA = n_sum + (size_t)node * 64;
    const float* sB = x + (size_t)node * 64;
    const float* sC = u + (size_t)batch[node] * 64;
    #pragma unroll
    for (int s = 0; s < 6; ++s) {
      const int off = (s & 1) * 32 + g * 8;
      if (s < 2)      A1[mt][s] = pack8s(sA + off, inv);
      else if (s < 4) A1[mt][s] = pack8(sB + off);
      else            A1[mt][s] = pack8(sC + off);
    }
  }
  f32x4 acc3[2][4];
  mlp3_core<6, NW1_RL, NW1_OFF, NW2_OFF, NW3_OFF>(sm, A1, b1v, b2v, hb, r15, g, acc3);
  #pragma unroll
  for (int mt = 0; mt < 2; ++mt)
    #pragma unroll
    for (int nt = 0; nt < 4; ++nt)
      #pragma unroll
      for (int i = 0; i < 4; ++i) {
        const int m = base + mt * 16 + g * 4 + i;
        if (m < NN) xn_out[(size_t)m * 64 + nt * 16 + r15] = acc3[mt][nt][i] + b3v[nt];
      }
}

// ---------------- batch segment starts (batch is sorted) ----------------
__global__ void bstart_kernel(const int* __restrict__ batch, int* __restrict__ bstart) {
  int tid = blockIdx.x * 256 + threadIdx.x;
  if (tid >= NN) return;
  int b = batch[tid];
  if (tid == 0) { for (int k = 0; k <= b; ++k) bstart[k] = 0; }
  else { int pb = batch[tid - 1]; for (int k = pb + 1; k <= b; ++k) bstart[k] = tid; }
  if (tid == NN - 1) { for (int k = b + 1; k <= BBATCH; ++k) bstart[k] = NN; }
}

// ---------------- per-batch segmented sums (no atomics) ----------------
__global__ void batch_sum_kernel(const float* __restrict__ xn, const float* __restrict__ n_sum,
                                 const int* __restrict__ deg, const int* __restrict__ bstart,
                                 float* __restrict__ nbsum, float* __restrict__ ebsum,
                                 int* __restrict__ ncnt, int* __restrict__ ecnt) {
  __shared__ float red0[256];
  __shared__ float red1[256];
  __shared__ int   redi[256];
  const int b = blockIdx.x;
  const int s = bstart[b], e = bstart[b + 1];
  const int t = threadIdx.x, c = t & 63, j0 = t >> 6;
  float xs = 0.f, ns = 0.f; int dc = 0;
  for (int j = s + j0; j < e; j += 4) {
    xs += xn[(size_t)j * 64 + c];
    ns += n_sum[(size_t)j * 64 + c];
    if (c == 0) dc += deg[j];
  }
  red0[t] = xs; red1[t] = ns; redi[t] = dc;
  __syncthreads();
  if (t < 128) { red0[t] += red0[t + 128]; red1[t] += red1[t + 128]; redi[t] += redi[t + 128]; }
  __syncthreads();
  if (t < 64) {
    float a0 = red0[t] + red0[t + 64];
    float a1 = red1[t] + red1[t + 64];
    nbsum[b * 64 + t] = a0;
    ebsum[b * 64 + t] = a1;
    if (t == 0) { ncnt[b] = e - s; ecnt[b] = redi[0] + redi[64]; }
  }
}

// ---------------- global MLP ----------------
__global__ __launch_bounds__(256, 1) void global_mlp_kernel(
    const float* __restrict__ u, const float* __restrict__ nbsum,
    const float* __restrict__ ebsum, const int* __restrict__ ncnt,
    const int* __restrict__ ecnt,
    const f16* __restrict__ w1t, const f16* __restrict__ w2t, const f16* __restrict__ w3t,
    const float* __restrict__ b1, const float* __restrict__ b2, const float* __restrict__ b3,
    float* __restrict__ un_out)
{
  __shared__ __align__(16) f16 sm[NLDS];
  const int t = threadIdx.x;
  for (int c = t; c < 3072; c += 256) { int r = c / 24, kc = c - r * 24;
    *(uint4*)&sm[NW1_OFF + r*NW1_RL + kc*8] = *(const uint4*)&w1t[r*192 + kc*8]; }
  for (int c = t; c < 2048; c += 256) { int r = c >> 4, kc = c & 15;
    *(uint4*)&sm[NW2_OFF + r*136 + kc*8] = *(const uint4*)&w2t[r*128 + kc*8]; }
  for (int c = t; c < 1024; c += 256) { int r = c >> 4, kc = c & 15;
    *(uint4*)&sm[NW3_OFF + r*136 + kc*8] = *(const uint4*)&w3t[r*128 + kc*8]; }
  __syncthreads();

  const int l = t & 63, w = t >> 6;
  const int r15 = l & 15, g = l >> 4;
  float b1v[8], b2v[8], b3v[4];
  #pragma unroll
  for (int nt = 0; nt < 8; ++nt) { b1v[nt] = b1[nt*16 + r15]; b2v[nt] = b2[nt*16 + r15]; }
  #pragma unroll
  for (int nt = 0; nt < 4; ++nt) b3v[nt] = b3[nt*16 + r15];
  const int hb = NH_OFF + w * (32 * 136);
  const int base = blockIdx.x * 128 + w * 32;

  f16x8 A1[2][8];
  #pragma unroll
  for (int mt = 0; mt < 2; ++mt) {
    const int r = base + mt * 16 + r15;
    const float invn = 1.0f / fmaxf((float)ncnt[r], 1.0f);
    const float inve = 1.0f / fmaxf((float)ecnt[r], 1.0f);
    const float* sA = u + (size_t)r * 64;
    const float* sB = nbsum + (size_t)r * 64;
    const float* sC = ebsum + (size_t)r * 64;
    #pragma unroll
    for (int s = 0; s < 6; ++s) {
      const int off = (s & 1) * 32 + g * 8;
      if (s < 2)      A1[mt][s] = pack8(sA + off);
      else if (s < 4) A1[mt][s] = pack8s(sB + off, invn);
      else            A1[mt][s] = pack8s(sC + off, inve);
    }
  }
  f32x4 acc3[2][4];
  mlp3_core<6, NW1_RL, NW1_OFF, NW2_OFF, NW3_OFF>(sm, A1, b1v, b2v, hb, r15, g, acc3);
  #pragma unroll
  for (int mt = 0; mt < 2; ++mt)
    #pragma unroll
    for (int nt = 0; nt < 4; ++nt)
      #pragma unroll
      for (int i = 0; i < 4; ++i) {
        const int m = base + mt * 16 + g * 4 + i;
        un_out[(size_t)m * 64 + nt * 16 + r15] = acc3[mt][nt][i] + b3v[nt];
      }
}

// ---------------- host launcher ----------------
extern "C" void kernel_launch(void* const* d_in, const int* in_sizes, int n_in,
                              void* d_out, int out_size, void* d_ws, size_t ws_size,
                              hipStream_t stream)
{
  (void)in_sizes; (void)n_in; (void)out_size; (void)ws_size;
  const float* x     = (const float*)d_in[0];
  const float* ea    = (const float*)d_in[1];
  const float* u     = (const float*)d_in[2];
  const int*   ei    = (const int*)d_in[3];
  const int*   batch = (const int*)d_in[4];
  const float* ew1 = (const float*)d_in[5];  const float* eb1 = (const float*)d_in[6];
  const float* ew2 = (const float*)d_in[7];  const float* eb2 = (const float*)d_in[8];
  const float* ew3 = (const float*)d_in[9];  const float* eb3 = (const float*)d_in[10];
  const float* nw1 = (const float*)d_in[11]; const float* nb1 = (const float*)d_in[12];
  const float* nw2 = (const float*)d_in[13]; const float* nb2 = (const float*)d_in[14];
  const float* nw3 = (const float*)d_in[15]; const float* nb3 = (const float*)d_in[16];
  const float* gw1 = (const float*)d_in[17]; const float* gb1 = (const float*)d_in[18];
  const float* gw2 = (const float*)d_in[19]; const float* gb2 = (const float*)d_in[20];
  const float* gw3 = (const float*)d_in[21]; const float* gb3 = (const float*)d_in[22];

  float* xn_out = (float*)d_out;
  float* e_out  = xn_out + (size_t)NN * DD;
  float* un_out = e_out + (size_t)EE * DD;

  char* p = (char*)d_ws;
  auto alloc = [&](size_t bytes) -> void* {
    void* r = (void*)p; p += (bytes + 255) & ~(size_t)255; return r;
  };
  f16* wtE1 = (f16*)alloc(256 * 128 * 2);
  f16* wtE2 = (f16*)alloc(128 * 128 * 2);
  f16* wtE3 = (f16*)alloc(128 * 64 * 2);
  f16* wtN1 = (f16*)alloc(192 * 128 * 2);
  f16* wtN2 = (f16*)alloc(128 * 128 * 2);
  f16* wtN3 = (f16*)alloc(128 * 64 * 2);
  f16* wtG1 = (f16*)alloc(192 * 128 * 2);
  f16* wtG2 = (f16*)alloc(128 * 128 * 2);
  f16* wtG3 = (f16*)alloc(128 * 64 * 2);
  int* deg    = (int*)alloc((size_t)NN * 4);
  int* offs   = (int*)alloc((size_t)(NN + 1) * 4);
  int* cursor = (int*)alloc((size_t)NN * 4);
  int* elist  = (int*)alloc((size_t)EE * 4);
  int* bstart = (int*)alloc((size_t)(BBATCH + 1) * 4);
  float* nbsum = (float*)alloc((size_t)BBATCH * 64 * 4);
  float* ebsum = (float*)alloc((size_t)BBATCH * 64 * 4);
  int* ncnt = (int*)alloc((size_t)BBATCH * 4);
  int* ecnt = (int*)alloc((size_t)BBATCH * 4);
  float* n_sum = (float*)alloc((size_t)NN * 64 * 4);

  // weight prep (transpose + f16 cast)
  transpose_cvt<<<dim3((256*128 + 255)/256), dim3(256), 0, stream>>>(ew1, wtE1, 256, 128);
  transpose_cvt<<<dim3((128*128 + 255)/256), dim3(256), 0, stream>>>(ew2, wtE2, 128, 128);
  transpose_cvt<<<dim3((128*64  + 255)/256), dim3(256), 0, stream>>>(ew3, wtE3, 128, 64);
  transpose_cvt<<<dim3((192*128 + 255)/256), dim3(256), 0, stream>>>(nw1, wtN1, 192, 128);
  transpose_cvt<<<dim3((128*128 + 255)/256), dim3(256), 0, stream>>>(nw2, wtN2, 128, 128);
  transpose_cvt<<<dim3((128*64  + 255)/256), dim3(256), 0, stream>>>(nw3, wtN3, 128, 64);
  transpose_cvt<<<dim3((192*128 + 255)/256), dim3(256), 0, stream>>>(gw1, wtG1, 192, 128);
  transpose_cvt<<<dim3((128*128 + 255)/256), dim3(256), 0, stream>>>(gw2, wtG2, 128, 128);
  transpose_cvt<<<dim3((128*64  + 255)/256), dim3(256), 0, stream>>>(gw3, wtG3, 128, 64);

  // CSR build
  hipMemsetAsync(deg, 0, (size_t)NN * 4, stream);
  count_kernel<<<dim3(6250), dim3(256), 0, stream>>>(ei, deg);
  scan_kernel<<<dim3(1), dim3(1024), 0, stream>>>(deg, offs, cursor);
  fill_kernel<<<dim3(6250), dim3(256), 0, stream>>>(ei, cursor, elist);

  // edge MLP (persistent blocks, 1 block/CU)
  edge_mlp_kernel<<<dim3(256), dim3(256), 0, stream>>>(
      x, ea, u, ei, batch, wtE1, wtE2, wtE3, eb1, eb2, eb3, e_out);

  // n_agg sums
  nsum_kernel<<<dim3(2048), dim3(256), 0, stream>>>(e_out, offs, elist, n_sum);

  // node MLP
  node_mlp_kernel<<<dim3((NN + 127) / 128), dim3(256), 0, stream>>>(
      x, u, batch, n_sum, deg, wtN1, wtN2, wtN3, nb1, nb2, nb3, xn_out);

  // per-batch reductions
  bstart_kernel<<<dim3((NN + 255) / 256), dim3(256), 0, stream>>>(batch, bstart);
  batch_sum_kernel<<<dim3(BBATCH), dim3(256), 0, stream>>>(
      xn_out, n_sum, deg, bstart, nbsum, ebsum, ncnt, ecnt);

  // global MLP
  global_mlp_kernel<<<dim3(2), dim3(256), 0, stream>>>(
      u, nbsum, ebsum, ncnt, ecnt, wtG1, wtG2, wtG3, gb1, gb2, gb3, un_out);
}

// Round 2
// 842.670 us; speedup vs baseline: 1.4395x; 1.4395x over previous
//
#include <hip/hip_runtime.h>

#define NN 50000
#define EE 1600000
#define BBATCH 256
#define DD 64

typedef _Float16 f16;
typedef _Float16 f16x8 __attribute__((ext_vector_type(8)));
typedef float f32x4 __attribute__((ext_vector_type(4)));

#define MFMA16(a,b,c) __builtin_amdgcn_mfma_f32_16x16x32_f16((a),(b),(c),0,0,0)

// ---------------- LDS layouts (in halves) ----------------
// Edge kernel: W1 [128][256->264], W2 [128][128->136], W3 [64][128->136], h 4x[32][136], bias 320 f32
constexpr int EW1_RL  = 264;
constexpr int EW1_OFF = 0;
constexpr int EW2_OFF = EW1_OFF + 128 * EW1_RL;   // 33792
constexpr int EW3_OFF = EW2_OFF + 128 * 136;      // 51200
constexpr int EH_OFF  = EW3_OFF + 64 * 136;       // 59904
constexpr int EB_OFF  = EH_OFF + 4 * 32 * 136;    // 77312 (byte 154624, 4B aligned)
constexpr int ELDS    = EB_OFF + 640;             // 77952 halves = 155904 B

// Node/global kernel: W1 [128][192->200], W2 [128][136], W3 [64][136], h 4x[32][136], bias
constexpr int NW1_RL  = 200;
constexpr int NW1_OFF = 0;
constexpr int NW2_OFF = NW1_OFF + 128 * NW1_RL;   // 25600
constexpr int NW3_OFF = NW2_OFF + 128 * 136;      // 43008
constexpr int NH_OFF  = NW3_OFF + 64 * 136;       // 51712
constexpr int NB_OFF  = NH_OFF + 4 * 32 * 136;    // 69120
constexpr int NLDS    = NB_OFF + 640;             // 69760 halves = 139520 B

// ---------------- helpers ----------------
__device__ __forceinline__ f16x8 pack8(const float* __restrict__ p) {
  f32x4 a = *(const f32x4*)p;
  f32x4 b = *(const f32x4*)(p + 4);
  f16x8 r;
  r[0]=(f16)a[0]; r[1]=(f16)a[1]; r[2]=(f16)a[2]; r[3]=(f16)a[3];
  r[4]=(f16)b[0]; r[5]=(f16)b[1]; r[6]=(f16)b[2]; r[7]=(f16)b[3];
  return r;
}
__device__ __forceinline__ f16x8 pack8s(const float* __restrict__ p, float sc) {
  f32x4 a = *(const f32x4*)p;
  f32x4 b = *(const f32x4*)(p + 4);
  a = a * sc; b = b * sc;
  f16x8 r;
  r[0]=(f16)a[0]; r[1]=(f16)a[1]; r[2]=(f16)a[2]; r[3]=(f16)a[3];
  r[4]=(f16)b[0]; r[5]=(f16)b[1]; r[6]=(f16)b[2]; r[7]=(f16)b[3];
  return r;
}
__device__ __forceinline__ f16x8 cvt8(f32x4 a, f32x4 b) {
  f16x8 r;
  r[0]=(f16)a[0]; r[1]=(f16)a[1]; r[2]=(f16)a[2]; r[3]=(f16)a[3];
  r[4]=(f16)b[0]; r[5]=(f16)b[1]; r[6]=(f16)b[2]; r[7]=(f16)b[3];
  return r;
}

// 3-layer MLP core. A layout: m=lane&15, k=(lane>>4)*8+j. Weights transposed [out][in]
// in LDS (B^T). D layout: n=lane&15, m=(lane>>4)*4+reg. h wave-private -> no barriers.
// Biases folded into accumulator init (C[m][n]=b[n] for all m). nt-halved to cap VGPRs.
template<int KSL, int W1RL, int W1O, int W2O, int W3O>
__device__ __forceinline__ void mlp3_core(f16* __restrict__ sm,
    const float* __restrict__ b1l, const float* __restrict__ b2l,
    const float* __restrict__ b3l,
    const f16x8 (&A1)[2][KSL], const int hb, const int r15, const int g,
    f32x4 (&acc3)[2][4])
{
  // ---- layer 1 (N=128), two nt-halves ----
  #pragma unroll
  for (int hh = 0; hh < 2; ++hh) {
    f32x4 acc[2][4];
    #pragma unroll
    for (int nt = 0; nt < 4; ++nt) {
      const float bv = b1l[(hh*4 + nt)*16 + r15];
      acc[0][nt] = (f32x4){bv, bv, bv, bv};
      acc[1][nt] = acc[0][nt];
    }
    #pragma unroll
    for (int s = 0; s < KSL; ++s) {
      #pragma unroll
      for (int nt = 0; nt < 4; ++nt) {
        const f16x8 bf = *(const f16x8*)&sm[W1O + ((hh*4+nt)*16 + r15) * W1RL + s*32 + g*8];
        acc[0][nt] = MFMA16(A1[0][s], bf, acc[0][nt]);
        acc[1][nt] = MFMA16(A1[1][s], bf, acc[1][nt]);
      }
    }
    #pragma unroll
    for (int mt = 0; mt < 2; ++mt)
      #pragma unroll
      for (int nt = 0; nt < 4; ++nt)
        #pragma unroll
        for (int i = 0; i < 4; ++i)
          sm[hb + (mt*16 + g*4 + i)*136 + (hh*4+nt)*16 + r15] =
              (f16)fmaxf(acc[mt][nt][i], 0.f);
  }

  // ---- layer 2 (K=128, N=128) ----
  f16x8 A2[2][4];
  #pragma unroll
  for (int mt = 0; mt < 2; ++mt)
    #pragma unroll
    for (int s = 0; s < 4; ++s)
      A2[mt][s] = *(const f16x8*)&sm[hb + (mt*16 + r15)*136 + s*32 + g*8];

  #pragma unroll
  for (int hh = 0; hh < 2; ++hh) {
    f32x4 acc[2][4];
    #pragma unroll
    for (int nt = 0; nt < 4; ++nt) {
      const float bv = b2l[(hh*4 + nt)*16 + r15];
      acc[0][nt] = (f32x4){bv, bv, bv, bv};
      acc[1][nt] = acc[0][nt];
    }
    #pragma unroll
    for (int s = 0; s < 4; ++s) {
      #pragma unroll
      for (int nt = 0; nt < 4; ++nt) {
        const f16x8 bf = *(const f16x8*)&sm[W2O + ((hh*4+nt)*16 + r15)*136 + s*32 + g*8];
        acc[0][nt] = MFMA16(A2[0][s], bf, acc[0][nt]);
        acc[1][nt] = MFMA16(A2[1][s], bf, acc[1][nt]);
      }
    }
    #pragma unroll
    for (int mt = 0; mt < 2; ++mt)
      #pragma unroll
      for (int nt = 0; nt < 4; ++nt)
        #pragma unroll
        for (int i = 0; i < 4; ++i)
          sm[hb + (mt*16 + g*4 + i)*136 + (hh*4+nt)*16 + r15] =
              (f16)fmaxf(acc[mt][nt][i], 0.f);
  }

  // ---- layer 3 (K=128, N=64) ----
  f16x8 A3[2][4];
  #pragma unroll
  for (int mt = 0; mt < 2; ++mt)
    #pragma unroll
    for (int s = 0; s < 4; ++s)
      A3[mt][s] = *(const f16x8*)&sm[hb + (mt*16 + r15)*136 + s*32 + g*8];

  #pragma unroll
  for (int nt = 0; nt < 4; ++nt) {
    const float bv = b3l[nt*16 + r15];
    acc3[0][nt] = (f32x4){bv, bv, bv, bv};
    acc3[1][nt] = acc3[0][nt];
  }
  #pragma unroll
  for (int s = 0; s < 4; ++s) {
    #pragma unroll
    for (int nt = 0; nt < 4; ++nt) {
      const f16x8 bf = *(const f16x8*)&sm[W3O + (nt*16 + r15)*136 + s*32 + g*8];
      acc3[0][nt] = MFMA16(A3[0][s], bf, acc3[0][nt]);
      acc3[1][nt] = MFMA16(A3[1][s], bf, acc3[1][nt]);
    }
  }
}

// ---------------- weight prep: transpose f32 [in][out] -> f16 [out][in] ----------------
__global__ void transpose_cvt(const float* __restrict__ w, f16* __restrict__ wt,
                              int in_dim, int out_dim) {
  int tid = blockIdx.x * 256 + threadIdx.x;
  int total = in_dim * out_dim;
  if (tid < total) {
    int o = tid / in_dim, i = tid - o * in_dim;
    wt[tid] = (f16)w[(size_t)i * out_dim + o];
  }
}

// ---------------- CSR build ----------------
__global__ void count_kernel(const int* __restrict__ ei, int* __restrict__ deg) {
  int tid = blockIdx.x * 256 + threadIdx.x;
  if (tid < EE) atomicAdd(&deg[ei[tid]], 1);
}

__global__ __launch_bounds__(1024) void scan_kernel(const int* __restrict__ deg,
                                                    int* __restrict__ offs,
                                                    int* __restrict__ cursor) {
  const int t = threadIdx.x;
  const int per = (NN + 1023) / 1024;
  const int s0 = t * per;
  int s1 = s0 + per; if (s1 > NN) s1 = NN;
  int sum = 0;
  for (int i = s0; i < s1; ++i) sum += deg[i];
  const int lane = t & 63, wid = t >> 6;
  int v = sum;
  #pragma unroll
  for (int off = 1; off < 64; off <<= 1) {
    int o = __shfl_up(v, off);
    if (lane >= off) v += o;
  }
  __shared__ int wsums[16];
  __shared__ int wexcl[16];
  if (lane == 63) wsums[wid] = v;
  __syncthreads();
  if (t == 0) { int run = 0; for (int k = 0; k < 16; ++k) { wexcl[k] = run; run += wsums[k]; } }
  __syncthreads();
  int run = wexcl[wid] + v - sum;
  for (int i = s0; i < s1; ++i) { int d = deg[i]; offs[i] = run; cursor[i] = run; run += d; }
  if (t == 1023) offs[NN] = run;
}

__global__ void fill_kernel(const int* __restrict__ ei, int* __restrict__ cursor,
                            int* __restrict__ elist) {
  int tid = blockIdx.x * 256 + threadIdx.x;
  if (tid < EE) {
    int r = ei[tid];
    int pos = atomicAdd(&cursor[r], 1);
    elist[pos] = tid;
  }
}

// ---------------- edge MLP (software-pipelined) ----------------
__global__ __launch_bounds__(256, 1) void edge_mlp_kernel(
    const float* __restrict__ x, const float* __restrict__ ea,
    const float* __restrict__ u, const int* __restrict__ ei,
    const int* __restrict__ batch,
    const f16* __restrict__ w1t, const f16* __restrict__ w2t, const f16* __restrict__ w3t,
    const float* __restrict__ b1, const float* __restrict__ b2, const float* __restrict__ b3,
    float* __restrict__ e_out)
{
  __shared__ __align__(16) f16 sm[ELDS];
  const int t = threadIdx.x;
  for (int c = t; c < 4096; c += 256) { int r = c >> 5, kc = c & 31;
    *(uint4*)&sm[EW1_OFF + r*EW1_RL + kc*8] = *(const uint4*)&w1t[r*256 + kc*8]; }
  for (int c = t; c < 2048; c += 256) { int r = c >> 4, kc = c & 15;
    *(uint4*)&sm[EW2_OFF + r*136 + kc*8] = *(const uint4*)&w2t[r*128 + kc*8]; }
  for (int c = t; c < 1024; c += 256) { int r = c >> 4, kc = c & 15;
    *(uint4*)&sm[EW3_OFF + r*136 + kc*8] = *(const uint4*)&w3t[r*128 + kc*8]; }
  float* bias = (float*)&sm[EB_OFF];
  if (t < 128) { bias[t] = b1[t]; bias[128 + t] = b2[t]; }
  if (t < 64)  { bias[256 + t] = b3[t]; }
  __syncthreads();

  const int l = t & 63, w = t >> 6;
  const int r15 = l & 15, g = l >> 4;
  const int hb = EH_OFF + w * (32 * 136);
  const float* b1l = bias;
  const float* b2l = bias + 128;
  const float* b3l = bias + 256;

  const int stride = gridDim.x;
  const int t0 = blockIdx.x;
  const int NT = EE / 128;

  // pipeline state
  int rC[2], cC[2], bC[2];   // indices for tile t+1 (gathers issued this body)
  int rN[2], cN[2], bN[2];   // indices for tile t+2 (arriving)
  f32x4 G[2][8][2];          // gathers in flight (f32)
  f16x8 A1[2][8];

  auto issueG = [&](const int (&rr)[2], const int (&cc)[2], const int (&bb)[2], int tt) {
    #pragma unroll
    for (int mt = 0; mt < 2; ++mt) {
      const float* s0p = x  + (size_t)rr[mt] * 64 + g * 8;
      const float* s1p = x  + (size_t)cc[mt] * 64 + g * 8;
      const float* s2p = ea + ((size_t)(tt * 128 + w * 32 + mt * 16 + r15)) * 64 + g * 8;
      const float* s3p = u  + (size_t)bb[mt] * 64 + g * 8;
      #pragma unroll
      for (int s = 0; s < 8; ++s) {
        const float* p = (s < 2 ? s0p : s < 4 ? s1p : s < 6 ? s2p : s3p) + (s & 1) * 32;
        G[mt][s][0] = *(const f32x4*)p;
        G[mt][s][1] = *(const f32x4*)(p + 4);
      }
    }
  };

  // prologue: idx(t0)+gathers(t0), idx(t0+stride)
  {
    int rr[2], cc[2], bb[2];
    #pragma unroll
    for (int mt = 0; mt < 2; ++mt) {
      const int eid = t0 * 128 + w * 32 + mt * 16 + r15;
      rr[mt] = ei[eid]; cc[mt] = ei[EE + eid];
    }
    #pragma unroll
    for (int mt = 0; mt < 2; ++mt) bb[mt] = batch[rr[mt]];
    issueG(rr, cc, bb, t0);
    int t1 = t0 + stride; if (t1 >= NT) t1 = t0;
    #pragma unroll
    for (int mt = 0; mt < 2; ++mt) {
      const int eid = t1 * 128 + w * 32 + mt * 16 + r15;
      rC[mt] = ei[eid]; cC[mt] = ei[EE + eid];
    }
    #pragma unroll
    for (int mt = 0; mt < 2; ++mt) bC[mt] = batch[rC[mt]];
  }

  for (int tile = t0; tile < NT; tile += stride) {
    // convert in-flight gathers for THIS tile (vmcnt wait lands here)
    #pragma unroll
    for (int mt = 0; mt < 2; ++mt)
      #pragma unroll
      for (int s = 0; s < 8; ++s)
        A1[mt][s] = cvt8(G[mt][s][0], G[mt][s][1]);

    // prefetch indices for t+2
    int t2 = tile + 2 * stride; if (t2 >= NT) t2 = t0;
    #pragma unroll
    for (int mt = 0; mt < 2; ++mt) {
      const int eid = t2 * 128 + w * 32 + mt * 16 + r15;
      rN[mt] = ei[eid]; cN[mt] = ei[EE + eid];
    }
    // issue gathers for t+1 (covered by this tile's compute)
    int t1 = tile + stride; if (t1 >= NT) t1 = t0;
    issueG(rC, cC, bC, t1);

    // compute
    f32x4 acc3[2][4];
    mlp3_core<8, EW1_RL, EW1_OFF, EW2_OFF, EW3_OFF>(sm, b1l, b2l, b3l, A1, hb, r15, g, acc3);

    // batch lookup for t+2 (rN arrived during the long compute above)
    #pragma unroll
    for (int mt = 0; mt < 2; ++mt) bN[mt] = batch[rN[mt]];

    // epilogue store (bias already in acc)
    const int base = tile * 128 + w * 32;
    #pragma unroll
    for (int mt = 0; mt < 2; ++mt)
      #pragma unroll
      for (int nt = 0; nt < 4; ++nt)
        #pragma unroll
        for (int i = 0; i < 4; ++i) {
          const int m = base + mt * 16 + g * 4 + i;
          e_out[(size_t)m * 64 + nt * 16 + r15] = acc3[mt][nt][i];
        }

    // rotate pipeline
    #pragma unroll
    for (int mt = 0; mt < 2; ++mt) { rC[mt] = rN[mt]; cC[mt] = cN[mt]; bC[mt] = bN[mt]; }
  }
}

// ---------------- n_agg sums via CSR gather (4-deep ILP) ----------------
__global__ void nsum_kernel(const float* __restrict__ e_src, const int* __restrict__ offs,
                            const int* __restrict__ elist, float* __restrict__ n_sum) {
  const int l = threadIdx.x & 63;
  const int wid = (blockIdx.x * blockDim.x + threadIdx.x) >> 6;
  const int nw = (gridDim.x * blockDim.x) >> 6;
  for (int node = wid; node < NN; node += nw) {
    const int s = offs[node], e = offs[node + 1];
    float acc = 0.f;
    int j = s;
    for (; j + 4 <= e; j += 4) {
      const int e0 = elist[j], e1 = elist[j+1], e2 = elist[j+2], e3 = elist[j+3];
      float v0 = e_src[(size_t)e0 * 64 + l];
      float v1 = e_src[(size_t)e1 * 64 + l];
      float v2 = e_src[(size_t)e2 * 64 + l];
      float v3 = e_src[(size_t)e3 * 64 + l];
      acc += (v0 + v1) + (v2 + v3);
    }
    for (; j < e; ++j) acc += e_src[(size_t)elist[j] * 64 + l];
    n_sum[(size_t)node * 64 + l] = acc;
  }
}

// ---------------- node MLP ----------------
__global__ __launch_bounds__(256, 1) void node_mlp_kernel(
    const float* __restrict__ x, const float* __restrict__ u,
    const int* __restrict__ batch, const float* __restrict__ n_sum,
    const int* __restrict__ deg,
    const f16* __restrict__ w1t, const f16* __restrict__ w2t, const f16* __restrict__ w3t,
    const float* __restrict__ b1, const float* __restrict__ b2, const float* __restrict__ b3,
    float* __restrict__ xn_out)
{
  __shared__ __align__(16) f16 sm[NLDS];
  const int t = threadIdx.x;
  for (int c = t; c < 3072; c += 256) { int r = c / 24, kc = c - r * 24;
    *(uint4*)&sm[NW1_OFF + r*NW1_RL + kc*8] = *(const uint4*)&w1t[r*192 + kc*8]; }
  for (int c = t; c < 2048; c += 256) { int r = c >> 4, kc = c & 15;
    *(uint4*)&sm[NW2_OFF + r*136 + kc*8] = *(const uint4*)&w2t[r*128 + kc*8]; }
  for (int c = t; c < 1024; c += 256) { int r = c >> 4, kc = c & 15;
    *(uint4*)&sm[NW3_OFF + r*136 + kc*8] = *(const uint4*)&w3t[r*128 + kc*8]; }
  float* bias = (float*)&sm[NB_OFF];
  if (t < 128) { bias[t] = b1[t]; bias[128 + t] = b2[t]; }
  if (t < 64)  { bias[256 + t] = b3[t]; }
  __syncthreads();

  const int l = t & 63, w = t >> 6;
  const int r15 = l & 15, g = l >> 4;
  const int hb = NH_OFF + w * (32 * 136);
  const int base = blockIdx.x * 128 + w * 32;

  f16x8 A1[2][6];
  #pragma unroll
  for (int mt = 0; mt < 2; ++mt) {
    int raw = base + mt * 16 + r15;
    int node = raw < NN ? raw : NN - 1;
    float inv = 1.0f / fmaxf((float)deg[node], 1.0f);
    const float* sA = n_sum + (size_t)node * 64;
    const float* sB = x + (size_t)node * 64;
    const float* sC = u + (size_t)batch[node] * 64;
    #pragma unroll
    for (int s = 0; s < 6; ++s) {
      const int off = (s & 1) * 32 + g * 8;
      if (s < 2)      A1[mt][s] = pack8s(sA + off, inv);
      else if (s < 4) A1[mt][s] = pack8(sB + off);
      else            A1[mt][s] = pack8(sC + off);
    }
  }
  f32x4 acc3[2][4];
  mlp3_core<6, NW1_RL, NW1_OFF, NW2_OFF, NW3_OFF>(sm, bias, bias + 128, bias + 256,
                                                  A1, hb, r15, g, acc3);
  #pragma unroll
  for (int mt = 0; mt < 2; ++mt)
    #pragma unroll
    for (int nt = 0; nt < 4; ++nt)
      #pragma unroll
      for (int i = 0; i < 4; ++i) {
        const int m = base + mt * 16 + g * 4 + i;
        if (m < NN) xn_out[(size_t)m * 64 + nt * 16 + r15] = acc3[mt][nt][i];
      }
}

// ---------------- batch segment starts (batch is sorted) ----------------
__global__ void bstart_kernel(const int* __restrict__ batch, int* __restrict__ bstart) {
  int tid = blockIdx.x * 256 + threadIdx.x;
  if (tid >= NN) return;
  int b = batch[tid];
  if (tid == 0) { for (int k = 0; k <= b; ++k) bstart[k] = 0; }
  else { int pb = batch[tid - 1]; for (int k = pb + 1; k <= b; ++k) bstart[k] = tid; }
  if (tid == NN - 1) { for (int k = b + 1; k <= BBATCH; ++k) bstart[k] = NN; }
}

// ---------------- per-batch segmented sums (no atomics) ----------------
__global__ void batch_sum_kernel(const float* __restrict__ xn, const float* __restrict__ n_sum,
                                 const int* __restrict__ deg, const int* __restrict__ bstart,
                                 float* __restrict__ nbsum, float* __restrict__ ebsum,
                                 int* __restrict__ ncnt, int* __restrict__ ecnt) {
  __shared__ float red0[256];
  __shared__ float red1[256];
  __shared__ int   redi[256];
  const int b = blockIdx.x;
  const int s = bstart[b], e = bstart[b + 1];
  const int t = threadIdx.x, c = t & 63, j0 = t >> 6;
  float xs = 0.f, ns = 0.f; int dc = 0;
  for (int j = s + j0; j < e; j += 4) {
    xs += xn[(size_t)j * 64 + c];
    ns += n_sum[(size_t)j * 64 + c];
    if (c == 0) dc += deg[j];
  }
  red0[t] = xs; red1[t] = ns; redi[t] = dc;
  __syncthreads();
  if (t < 128) { red0[t] += red0[t + 128]; red1[t] += red1[t + 128]; redi[t] += redi[t + 128]; }
  __syncthreads();
  if (t < 64) {
    float a0 = red0[t] + red0[t + 64];
    float a1 = red1[t] + red1[t + 64];
    nbsum[b * 64 + t] = a0;
    ebsum[b * 64 + t] = a1;
    if (t == 0) { ncnt[b] = e - s; ecnt[b] = redi[0] + redi[64]; }
  }
}

// ---------------- global MLP ----------------
__global__ __launch_bounds__(256, 1) void global_mlp_kernel(
    const float* __restrict__ u, const float* __restrict__ nbsum,
    const float* __restrict__ ebsum, const int* __restrict__ ncnt,
    const int* __restrict__ ecnt,
    const f16* __restrict__ w1t, const f16* __restrict__ w2t, const f16* __restrict__ w3t,
    const float* __restrict__ b1, const float* __restrict__ b2, const float* __restrict__ b3,
    float* __restrict__ un_out)
{
  __shared__ __align__(16) f16 sm[NLDS];
  const int t = threadIdx.x;
  for (int c = t; c < 3072; c += 256) { int r = c / 24, kc = c - r * 24;
    *(uint4*)&sm[NW1_OFF + r*NW1_RL + kc*8] = *(const uint4*)&w1t[r*192 + kc*8]; }
  for (int c = t; c < 2048; c += 256) { int r = c >> 4, kc = c & 15;
    *(uint4*)&sm[NW2_OFF + r*136 + kc*8] = *(const uint4*)&w2t[r*128 + kc*8]; }
  for (int c = t; c < 1024; c += 256) { int r = c >> 4, kc = c & 15;
    *(uint4*)&sm[NW3_OFF + r*136 + kc*8] = *(const uint4*)&w3t[r*128 + kc*8]; }
  float* bias = (float*)&sm[NB_OFF];
  if (t < 128) { bias[t] = b1[t]; bias[128 + t] = b2[t]; }
  if (t < 64)  { bias[256 + t] = b3[t]; }
  __syncthreads();

  const int l = t & 63, w = t >> 6;
  const int r15 = l & 15, g = l >> 4;
  const int hb = NH_OFF + w * (32 * 136);
  const int base = blockIdx.x * 128 + w * 32;

  f16x8 A1[2][6];
  #pragma unroll
  for (int mt = 0; mt < 2; ++mt) {
    const int r = base + mt * 16 + r15;
    const float invn = 1.0f / fmaxf((float)ncnt[r], 1.0f);
    const float inve = 1.0f / fmaxf((float)ecnt[r], 1.0f);
    const float* sA = u + (size_t)r * 64;
    const float* sB = nbsum + (size_t)r * 64;
    const float* sC = ebsum + (size_t)r * 64;
    #pragma unroll
    for (int s = 0; s < 6; ++s) {
      const int off = (s & 1) * 32 + g * 8;
      if (s < 2)      A1[mt][s] = pack8(sA + off);
      else if (s < 4) A1[mt][s] = pack8s(sB + off, invn);
      else            A1[mt][s] = pack8s(sC + off, inve);
    }
  }
  f32x4 acc3[2][4];
  mlp3_core<6, NW1_RL, NW1_OFF, NW2_OFF, NW3_OFF>(sm, bias, bias + 128, bias + 256,
                                                  A1, hb, r15, g, acc3);
  #pragma unroll
  for (int mt = 0; mt < 2; ++mt)
    #pragma unroll
    for (int nt = 0; nt < 4; ++nt)
      #pragma unroll
      for (int i = 0; i < 4; ++i) {
        const int m = base + mt * 16 + g * 4 + i;
        un_out[(size_t)m * 64 + nt * 16 + r15] = acc3[mt][nt][i];
      }
}

// ---------------- host launcher ----------------
extern "C" void kernel_launch(void* const* d_in, const int* in_sizes, int n_in,
                              void* d_out, int out_size, void* d_ws, size_t ws_size,
                              hipStream_t stream)
{
  (void)in_sizes; (void)n_in; (void)out_size; (void)ws_size;
  const float* x     = (const float*)d_in[0];
  const float* ea    = (const float*)d_in[1];
  const float* u     = (const float*)d_in[2];
  const int*   ei    = (const int*)d_in[3];
  const int*   batch = (const int*)d_in[4];
  const float* ew1 = (const float*)d_in[5];  const float* eb1 = (const float*)d_in[6];
  const float* ew2 = (const float*)d_in[7];  const float* eb2 = (const float*)d_in[8];
  const float* ew3 = (const float*)d_in[9];  const float* eb3 = (const float*)d_in[10];
  const float* nw1 = (const float*)d_in[11]; const float* nb1 = (const float*)d_in[12];
  const float* nw2 = (const float*)d_in[13]; const float* nb2 = (const float*)d_in[14];
  const float* nw3 = (const float*)d_in[15]; const float* nb3 = (const float*)d_in[16];
  const float* gw1 = (const float*)d_in[17]; const float* gb1 = (const float*)d_in[18];
  const float* gw2 = (const float*)d_in[19]; const float* gb2 = (const float*)d_in[20];
  const float* gw3 = (const float*)d_in[21]; const float* gb3 = (const float*)d_in[22];

  float* xn_out = (float*)d_out;
  float* e_out  = xn_out + (size_t)NN * DD;
  float* un_out = e_out + (size_t)EE * DD;

  char* p = (char*)d_ws;
  auto alloc = [&](size_t bytes) -> void* {
    void* r = (void*)p; p += (bytes + 255) & ~(size_t)255; return r;
  };
  f16* wtE1 = (f16*)alloc(256 * 128 * 2);
  f16* wtE2 = (f16*)alloc(128 * 128 * 2);
  f16* wtE3 = (f16*)alloc(128 * 64 * 2);
  f16* wtN1 = (f16*)alloc(192 * 128 * 2);
  f16* wtN2 = (f16*)alloc(128 * 128 * 2);
  f16* wtN3 = (f16*)alloc(128 * 64 * 2);
  f16* wtG1 = (f16*)alloc(192 * 128 * 2);
  f16* wtG2 = (f16*)alloc(128 * 128 * 2);
  f16* wtG3 = (f16*)alloc(128 * 64 * 2);
  int* deg    = (int*)alloc((size_t)NN * 4);
  int* offs   = (int*)alloc((size_t)(NN + 1) * 4);
  int* cursor = (int*)alloc((size_t)NN * 4);
  int* elist  = (int*)alloc((size_t)EE * 4);
  int* bstart = (int*)alloc((size_t)(BBATCH + 1) * 4);
  float* nbsum = (float*)alloc((size_t)BBATCH * 64 * 4);
  float* ebsum = (float*)alloc((size_t)BBATCH * 64 * 4);
  int* ncnt = (int*)alloc((size_t)BBATCH * 4);
  int* ecnt = (int*)alloc((size_t)BBATCH * 4);
  float* n_sum = (float*)alloc((size_t)NN * 64 * 4);

  transpose_cvt<<<dim3((256*128 + 255)/256), dim3(256), 0, stream>>>(ew1, wtE1, 256, 128);
  transpose_cvt<<<dim3((128*128 + 255)/256), dim3(256), 0, stream>>>(ew2, wtE2, 128, 128);
  transpose_cvt<<<dim3((128*64  + 255)/256), dim3(256), 0, stream>>>(ew3, wtE3, 128, 64);
  transpose_cvt<<<dim3((192*128 + 255)/256), dim3(256), 0, stream>>>(nw1, wtN1, 192, 128);
  transpose_cvt<<<dim3((128*128 + 255)/256), dim3(256), 0, stream>>>(nw2, wtN2, 128, 128);
  transpose_cvt<<<dim3((128*64  + 255)/256), dim3(256), 0, stream>>>(nw3, wtN3, 128, 64);
  transpose_cvt<<<dim3((192*128 + 255)/256), dim3(256), 0, stream>>>(gw1, wtG1, 192, 128);
  transpose_cvt<<<dim3((128*128 + 255)/256), dim3(256), 0, stream>>>(gw2, wtG2, 128, 128);
  transpose_cvt<<<dim3((128*64  + 255)/256), dim3(256), 0, stream>>>(gw3, wtG3, 128, 64);

  hipMemsetAsync(deg, 0, (size_t)NN * 4, stream);
  count_kernel<<<dim3(6250), dim3(256), 0, stream>>>(ei, deg);
  scan_kernel<<<dim3(1), dim3(1024), 0, stream>>>(deg, offs, cursor);
  fill_kernel<<<dim3(6250), dim3(256), 0, stream>>>(ei, cursor, elist);

  edge_mlp_kernel<<<dim3(256), dim3(256), 0, stream>>>(
      x, ea, u, ei, batch, wtE1, wtE2, wtE3, eb1, eb2, eb3, e_out);

  nsum_kernel<<<dim3(2048), dim3(256), 0, stream>>>(e_out, offs, elist, n_sum);

  node_mlp_kernel<<<dim3((NN + 127) / 128), dim3(256), 0, stream>>>(
      x, u, batch, n_sum, deg, wtN1, wtN2, wtN3, nb1, nb2, nb3, xn_out);

  bstart_kernel<<<dim3((NN + 255) / 256), dim3(256), 0, stream>>>(batch, bstart);
  batch_sum_kernel<<<dim3(BBATCH), dim3(256), 0, stream>>>(
      xn_out, n_sum, deg, bstart, nbsum, ebsum, ncnt, ecnt);

  global_mlp_kernel<<<dim3(2), dim3(256), 0, stream>>>(
      u, nbsum, ebsum, ncnt, ecnt, wtG1, wtG2, wtG3, gb1, gb2, gb3, un_out);
}